// Round 5
// baseline (5373.125 us; speedup 1.0000x reference)
//
#include <hip/hip_runtime.h>
#include <math.h>

#define Bb 256
#define Tt 512
#define Ii 128
#define Hh 256
#define Ss 4
#define G4 1024  // 4*H gate rows

typedef _Float16 half2t __attribute__((ext_vector_type(2)));
union W16 { uint4 u; half2t h[4]; };

__device__ __forceinline__ float dot8(uint4 w, uint4 hv, float acc) {
  W16 a; a.u = w; W16 b; b.u = hv;
#if __has_builtin(__builtin_amdgcn_fdot2)
  acc = __builtin_amdgcn_fdot2(a.h[0], b.h[0], acc, false);
  acc = __builtin_amdgcn_fdot2(a.h[1], b.h[1], acc, false);
  acc = __builtin_amdgcn_fdot2(a.h[2], b.h[2], acc, false);
  acc = __builtin_amdgcn_fdot2(a.h[3], b.h[3], acc, false);
#else
#pragma unroll
  for (int k = 0; k < 4; k++)
    acc += (float)a.h[k].x * (float)b.h[k].x + (float)a.h[k].y * (float)b.h[k].y;
#endif
  return acc;
}

// ---------------- kernel 1: lengths[b] = max(sum(mask[b,:]), 1) ----------------
__global__ void k_len(const int* __restrict__ mask, int* __restrict__ len) {
  int b = blockIdx.x, tid = threadIdx.x;
  int c = (mask[b * Tt + tid] != 0) + (mask[b * Tt + 256 + tid] != 0);
#pragma unroll
  for (int off = 32; off > 0; off >>= 1) c += __shfl_down(c, off, 64);
  __shared__ int red[4];
  if ((tid & 63) == 0) red[tid >> 6] = c;
  __syncthreads();
  if (tid == 0) {
    int t = red[0] + red[1] + red[2] + red[3];
    len[b] = t < 1 ? 1 : t;
  }
}

// ---------------- kernel 1b: sort batch indices by length (rank sort) ----------
// ord[rank] = batch index, ascending length; a quad of adjacent ranks shares
// (almost always) the same segment schedule -> one weight load serves 4 batches.
__global__ void k_sort(const int* __restrict__ len, int* __restrict__ ord) {
  const int b = threadIdx.x;  // one block, 256 threads
  __shared__ int Ls[Bb];
  Ls[b] = len[b];
  __syncthreads();
  const int Lb = Ls[b];
  int rank = 0;
  for (int j = 0; j < Bb; j++) {
    int Lj = Ls[j];
    rank += (Lj < Lb) || (Lj == Lb && j < b);
  }
  ord[rank] = b;
}

// ---------------- kernel 2: weight transforms to fp16 [s][i/8][o] -------------
// wt_hh16[(s*32+i8)*1024+o] = 8 halfs {W_hh[s][o][8i8..8i8+7]}
// wt_ih16[(s*16+i8)*1024+o] = 8 halfs {W_ih[s][o][8i8..8i8+7]}
__global__ void k_tr(const float* __restrict__ W_ih, const float* __restrict__ W_hh,
                     uint4* __restrict__ wt_hh16, uint4* __restrict__ wt_ih16) {
  int id = blockIdx.x * blockDim.x + threadIdx.x;
  const int NH16 = Ss * 32 * G4;  // 131072
  const int NI16 = Ss * 16 * G4;  // 65536
  if (id < NH16) {
    int o = id % G4, i8 = (id / G4) % 32, s = id / (G4 * 32);
    const float* src = W_hh + ((size_t)(s * G4 + o)) * Hh + 8 * i8;
    W16 w;
#pragma unroll
    for (int k = 0; k < 4; k++) {
      w.h[k].x = (_Float16)src[2 * k];
      w.h[k].y = (_Float16)src[2 * k + 1];
    }
    wt_hh16[id] = w.u;
  } else if (id < NH16 + NI16) {
    int id3 = id - NH16;
    int o = id3 % G4, i8 = (id3 / G4) % 16, s = id3 / (G4 * 16);
    const float* src = W_ih + ((size_t)(s * G4 + o)) * Ii + 8 * i8;
    W16 w;
#pragma unroll
    for (int k = 0; k < 4; k++) {
      w.h[k].x = (_Float16)src[2 * k];
      w.h[k].y = (_Float16)src[2 * k + 1];
    }
    wt_ih16[id3] = w.u;
  }
}

// ---------------- kernel 3: QUAD fused recurrence ------------------------------
// Block p handles batches ord[4p..4p+3] (length-sorted). 1024 threads; thread r
// owns gate row r for ALL 4 batches: each weight uint4 loaded once from L2 is
// dotted against 4 h (or x) vectors -> 4x register-level weight reuse.
// Thread r also owns the c-state of (v=r>>8, u=r&255). No gx workspace needed.
__global__ __launch_bounds__(1024, 1) void k_lstm_q4(
    const float* __restrict__ x, const uint4* __restrict__ wt_hh16,
    const uint4* __restrict__ wt_ih16, const float* __restrict__ b_ih,
    const float* __restrict__ b_hh, const int* __restrict__ len,
    const int* __restrict__ ord, float* __restrict__ out) {
  const int p = blockIdx.x;
  const int r = threadIdx.x;  // gate row 0..1023
  int bq[4], Lq[4];
#pragma unroll
  for (int q = 0; q < 4; q++) {
    bq[q] = ord[4 * p + q];
    Lq[q] = len[bq[q]];
  }
  const int Lmax = Lq[3];  // ascending sort
  float bias[4];           // combined bias for this row, all 4 segments
#pragma unroll
  for (int s = 0; s < 4; s++) bias[s] = b_ih[s * G4 + r] + b_hh[s * G4 + r];

  __shared__ __align__(16) _Float16 h_h[4][Hh];
  __shared__ __align__(16) _Float16 x_h[4][Ii];
  __shared__ float g_act[4][G4];
  const int v = r >> 8;   // epilogue batch slot
  const int u = r & 255;  // epilogue unit
  const int gate = r >> 8;
  h_h[v][u] = (_Float16)0.f;
  float c = 0.f;
  const float* xsrc = (r < 512)
      ? x + ((size_t)bq[r >> 7] * Tt) * Ii + (r & 127) : (const float*)nullptr;
  const uint4(*h4)[Hh / 8] = (const uint4(*)[Hh / 8])h_h;
  const uint4(*x4)[Ii / 8] = (const uint4(*)[Ii / 8])x_h;
  float* outv = out + (size_t)bq[v] * Tt * Hh + u;
  float* lastv = out + (size_t)Bb * Tt * Hh + (size_t)bq[v] * Hh + u;
  const int Lv = Lq[v];

  for (int t = 0; t < Tt; t++) {
    if (t < Lmax) {  // block-uniform
      if (r < 512) x_h[r >> 7][r & 127] = (_Float16)xsrc[(size_t)t * Ii];
      int s[4];
#pragma unroll
      for (int q = 0; q < 4; q++) {
        int sq = t * Ss / Lq[q];
        s[q] = sq > Ss - 1 ? Ss - 1 : sq;
      }
#pragma unroll
      for (int q = 0; q < 3; q++)
        if (t >= Lq[q]) s[q] = s[3];  // inactive batches ride q=3's stream
      float a0 = bias[s[0]], a1 = bias[s[1]], a2 = bias[s[2]], a3 = bias[s[3]];
      __syncthreads();  // B1: prev-step h_h writes + x_h staging visible
      if (s[0] == s[3]) {  // one shared stream (common case; s is monotone)
        const uint4* wb = wt_hh16 + (size_t)s[0] * 32 * G4 + r;
        const uint4* wi = wt_ih16 + (size_t)s[0] * 16 * G4 + r;
#pragma unroll 8
        for (int i8 = 0; i8 < 32; i8++) {
          uint4 w = wb[i8 * G4];
          a0 = dot8(w, h4[0][i8], a0);
          a1 = dot8(w, h4[1][i8], a1);
          a2 = dot8(w, h4[2][i8], a2);
          a3 = dot8(w, h4[3][i8], a3);
        }
#pragma unroll 8
        for (int i8 = 0; i8 < 16; i8++) {
          uint4 w = wi[i8 * G4];
          a0 = dot8(w, x4[0][i8], a0);
          a1 = dot8(w, x4[1][i8], a1);
          a2 = dot8(w, x4[2][i8], a2);
          a3 = dot8(w, x4[3][i8], a3);
        }
      } else if (s[0] == s[1] && s[2] == s[3]) {  // two streams
        const uint4* wbA = wt_hh16 + (size_t)s[0] * 32 * G4 + r;
        const uint4* wbB = wt_hh16 + (size_t)s[2] * 32 * G4 + r;
        const uint4* wiA = wt_ih16 + (size_t)s[0] * 16 * G4 + r;
        const uint4* wiB = wt_ih16 + (size_t)s[2] * 16 * G4 + r;
#pragma unroll 4
        for (int i8 = 0; i8 < 32; i8++) {
          uint4 wA = wbA[i8 * G4];
          uint4 wB = wbB[i8 * G4];
          a0 = dot8(wA, h4[0][i8], a0);
          a1 = dot8(wA, h4[1][i8], a1);
          a2 = dot8(wB, h4[2][i8], a2);
          a3 = dot8(wB, h4[3][i8], a3);
        }
#pragma unroll 4
        for (int i8 = 0; i8 < 16; i8++) {
          uint4 wA = wiA[i8 * G4];
          uint4 wB = wiB[i8 * G4];
          a0 = dot8(wA, x4[0][i8], a0);
          a1 = dot8(wA, x4[1][i8], a1);
          a2 = dot8(wB, x4[2][i8], a2);
          a3 = dot8(wB, x4[3][i8], a3);
        }
      } else {  // rare: fully general
        const uint4* wb0 = wt_hh16 + (size_t)s[0] * 32 * G4 + r;
        const uint4* wb1 = wt_hh16 + (size_t)s[1] * 32 * G4 + r;
        const uint4* wb2 = wt_hh16 + (size_t)s[2] * 32 * G4 + r;
        const uint4* wb3 = wt_hh16 + (size_t)s[3] * 32 * G4 + r;
#pragma unroll 4
        for (int i8 = 0; i8 < 32; i8++) {
          a0 = dot8(wb0[i8 * G4], h4[0][i8], a0);
          a1 = dot8(wb1[i8 * G4], h4[1][i8], a1);
          a2 = dot8(wb2[i8 * G4], h4[2][i8], a2);
          a3 = dot8(wb3[i8 * G4], h4[3][i8], a3);
        }
        const uint4* wi0 = wt_ih16 + (size_t)s[0] * 16 * G4 + r;
        const uint4* wi1 = wt_ih16 + (size_t)s[1] * 16 * G4 + r;
        const uint4* wi2 = wt_ih16 + (size_t)s[2] * 16 * G4 + r;
        const uint4* wi3 = wt_ih16 + (size_t)s[3] * 16 * G4 + r;
#pragma unroll 4
        for (int i8 = 0; i8 < 16; i8++) {
          a0 = dot8(wi0[i8 * G4], x4[0][i8], a0);
          a1 = dot8(wi1[i8 * G4], x4[1][i8], a1);
          a2 = dot8(wi2[i8 * G4], x4[2][i8], a2);
          a3 = dot8(wi3[i8 * G4], x4[3][i8], a3);
        }
      }
      if (gate == 2) {  // g gate rows: tanh; others: sigmoid
        g_act[0][r] = tanhf(a0);
        g_act[1][r] = tanhf(a1);
        g_act[2][r] = tanhf(a2);
        g_act[3][r] = tanhf(a3);
      } else {
        g_act[0][r] = 1.f / (1.f + expf(-a0));
        g_act[1][r] = 1.f / (1.f + expf(-a1));
        g_act[2][r] = 1.f / (1.f + expf(-a2));
        g_act[3][r] = 1.f / (1.f + expf(-a3));
      }
      __syncthreads();  // B2: h_h/x_h reads done; g_act visible
      if (t < Lv) {
        float ig = g_act[v][u];
        float fg = g_act[v][u + 256];
        float gg = g_act[v][u + 512];
        float og = g_act[v][u + 768];
        c = fg * c + ig * gg;
        float h = og * tanhf(c);
        h_h[v][u] = (_Float16)h;
        outv[(size_t)t * Hh] = h;
        if (t == Lv - 1) *lastv = h;
      } else {
        outv[(size_t)t * Hh] = 0.f;
      }
    } else {
      outv[(size_t)t * Hh] = 0.f;
    }
  }
}

extern "C" void kernel_launch(void* const* d_in, const int* in_sizes, int n_in,
                              void* d_out, int out_size, void* d_ws, size_t ws_size,
                              hipStream_t stream) {
  const float* x = (const float*)d_in[0];
  const int* mask = (const int*)d_in[1];
  const float* W_ih = (const float*)d_in[2];
  const float* W_hh = (const float*)d_in[3];
  const float* b_ih = (const float*)d_in[4];
  const float* b_hh = (const float*)d_in[5];
  float* out = (float*)d_out;
  char* ws = (char*)d_ws;

  const size_t HH16_OFF = 0;
  const size_t HH16_BYTES = (size_t)Ss * 32 * G4 * 16;  // 2 MiB
  const size_t IH16_OFF = HH16_OFF + HH16_BYTES;
  const size_t IH16_BYTES = (size_t)Ss * 16 * G4 * 16;  // 1 MiB
  const size_t LEN_OFF = IH16_OFF + IH16_BYTES;
  const size_t ORD_OFF = LEN_OFF + 4096;

  uint4* wt_hh16 = (uint4*)(ws + HH16_OFF);
  uint4* wt_ih16 = (uint4*)(ws + IH16_OFF);
  int* len = (int*)(ws + LEN_OFF);
  int* ord = (int*)(ws + ORD_OFF);

  k_len<<<Bb, 256, 0, stream>>>(mask, len);
  k_sort<<<1, 256, 0, stream>>>(len, ord);
  k_tr<<<768, 256, 0, stream>>>(W_ih, W_hh, wt_hh16, wt_ih16);
  k_lstm_q4<<<Bb / 4, 1024, 0, stream>>>(x, wt_hh16, wt_ih16, b_ih, b_hh, len,
                                         ord, out);
}